// Round 3
// baseline (11.652 us; speedup 1.0000x reference)
//
#include <hip/hip_runtime.h>
#include <hip/hip_bf16.h>

#define NC 21
#define LAMBDA 0.5f

// Slot protocol (self-restoring across graph replays, no init needed):
//   writer:  atomicExch(slot, mask | (SIG<<21))     -- mask < 2^21
//   reader:  v = atomicExch(slot, SENT); accept iff (v>>21)==SIG
// Consuming a value leaves SENT (invalid), so every replay starts "unwritten".
// Poison 0xAAAAAAAA (top11=0x555), zeros (0x000), SENT (top11=0x400) all fail
// the SIG=0x2B3 check. Device-scope atomics -> cross-XCD coherent.
#define SIG  0x2B3u
#define SIGW (SIG << 21)
#define SENT 0x80000000u

// B=8, 262144 labels/image = 65536 int4/image, 524288 int4 total.
// Blocks 0..255: scan 2048 int4 each (32 blocks per batch, 4 waves/block,
//   8 independent int4 loads/thread, wave-64 shfl-OR, one atomicExch per wave
//   into bm[blk*4+wave]). No LDS, no barriers -- waves retire independently.
// Block 256: computes the 168 (b,c) left/right margin terms into registers
//   (overlapped with the scan), then polls the 1024 slots, reduces, writes out.
__global__ __launch_bounds__(256) void caps_fused(
        const int* __restrict__ labels, const float* __restrict__ caps,
        unsigned* bm, float* __restrict__ out) {
    int t = threadIdx.x;
    if (blockIdx.x < 256) {
        const int4* L = reinterpret_cast<const int4*>(labels)
                        + (size_t)blockIdx.x * 2048;
        unsigned m = 0;
        #pragma unroll
        for (int k = 0; k < 8; ++k) {
            int4 v = L[t + k * 256];
            if ((unsigned)v.x < (unsigned)NC) m |= 1u << v.x;
            if ((unsigned)v.y < (unsigned)NC) m |= 1u << v.y;
            if ((unsigned)v.z < (unsigned)NC) m |= 1u << v.z;
            if ((unsigned)v.w < (unsigned)NC) m |= 1u << v.w;
        }
        #pragma unroll
        for (int s = 1; s < 64; s <<= 1) m |= __shfl_xor(m, s, 64);
        if ((t & 63) == 0)
            atomicExch(bm + blockIdx.x * 4 + (t >> 6), m | SIGW);
        return;
    }

    // ---- finalize block (blockIdx.x == 256) ----
    // Caps math first: overlaps with the scan blocks still running.
    float l = 0.0f, r = 0.0f;
    if (t < 8 * NC) {
        const float* p = caps + t * 16;
        float s2 = 0.0f;
        #pragma unroll
        for (int d = 0; d < 16; ++d) { float x = p[d]; s2 += x * x; }
        float len = sqrtf(s2);
        l = fmaxf(0.9f - len, 0.0f);  l *= l;
        r = fmaxf(len - 0.1f, 0.0f);  r *= r;
    }

    // Poll 4 slots per thread. Slot s belongs to batch s/128; thread t owns
    // slots 4t..4t+3, all in batch t>>5 (aligned 32-thread groups per batch).
    unsigned acc = 0, got = 0;
    unsigned* base = bm + t * 4;
    while (got != 0xFu) {
        #pragma unroll
        for (int k = 0; k < 4; ++k) {
            if (!(got & (1u << k))) {
                unsigned v = atomicExch(base + k, SENT);
                if ((v >> 21) == SIG) { acc |= v & 0x1FFFFFu; got |= 1u << k; }
            }
        }
        if (got != 0xFu) __builtin_amdgcn_s_sleep(1);
    }

    // OR-reduce across each aligned 32-lane group -> pres[batch]
    #pragma unroll
    for (int s = 16; s; s >>= 1) acc |= __shfl_xor(acc, s, 64);
    __shared__ unsigned pres[8];
    __shared__ float psum[4];
    if ((t & 31) == 0) pres[t >> 5] = acc;
    __syncthreads();

    float v = 0.0f;
    if (t < 8 * NC) {
        int bb = t / NC, c = t % NC;
        v = ((pres[bb] >> c) & 1u) ? l : LAMBDA * r;
    }
    #pragma unroll
    for (int s = 32; s; s >>= 1) v += __shfl_xor(v, s, 64);
    if ((t & 63) == 0) psum[t >> 6] = v;
    __syncthreads();
    if (t == 0) out[0] = (psum[0] + psum[1] + psum[2] + psum[3]) * 0.125f;
}

extern "C" void kernel_launch(void* const* d_in, const int* in_sizes, int n_in,
                              void* d_out, int out_size, void* d_ws, size_t ws_size,
                              hipStream_t stream) {
    const float* caps   = (const float*)d_in[0];  // [8,21,16] f32
    const int*   labels = (const int*)d_in[1];    // [8,512,512] i32
    float* out = (float*)d_out;
    unsigned* bm = (unsigned*)d_ws;               // 1024 slots = 4 KiB

    caps_fused<<<257, 256, 0, stream>>>(labels, caps, bm, out);
}